// Round 1
// baseline (3373.038 us; speedup 1.0000x reference)
//
#include <hip/hip_runtime.h>
#include <hip/hip_bf16.h>
#include <cstdint>

// Problem constants
#define V_  32000
#define E_  512
#define H_  1024
#define CTX_ 1024
#define T_  64
#define B_  64
#define FH_ 4096   // 4*H

typedef __attribute__((ext_vector_type(8))) __bf16 bf16x8;
typedef __attribute__((ext_vector_type(4))) __bf16 bf16x4;
typedef __attribute__((ext_vector_type(4))) float f32x4;

#define DEV static __device__ __forceinline__

DEV __bf16 f2bf(float f) {
    union { float f; unsigned u; } v; v.f = f;
    unsigned r = (v.u + 0x7FFFu + ((v.u >> 16) & 1u)) >> 16;
    unsigned short s = (unsigned short)r;
    return __builtin_bit_cast(__bf16, s);
}

DEV float sigm(float x) { return 1.0f / (1.0f + __expf(-x)); }

// async global->LDS, 16B per lane; LDS dest = wave-uniform base + lane*16
#define GL(g, l) __builtin_amdgcn_global_load_lds(                         \
    (const __attribute__((address_space(1))) void*)(g),                    \
    (__attribute__((address_space(3))) void*)(l), 16, 0, 0)

// ---------------- casts / gathers ----------------
__global__ __launch_bounds__(256) void k_cast(const float* __restrict__ src,
                                              __bf16* __restrict__ dst, int n4) {
    int i = blockIdx.x * 256 + threadIdx.x;
    if (i >= n4) return;
    float4 v = *(const float4*)(src + (size_t)i * 4);
    bf16x4 o; o[0]=f2bf(v.x); o[1]=f2bf(v.y); o[2]=f2bf(v.z); o[3]=f2bf(v.w);
    *(bf16x4*)(dst + (size_t)i * 4) = o;
}

// W_ihE = bf16(W_ih[:, CTX:CTX+E])  -> [4096][512]
__global__ __launch_bounds__(256) void k_cast_wihe(const float* __restrict__ Wih,
                                                   __bf16* __restrict__ dst) {
    int i = blockIdx.x * 256 + threadIdx.x;   // 524288 threads, 4 elems each
    int e = i * 4, j = e >> 9, k = e & 511;
    float4 v = *(const float4*)(Wih + (size_t)j * (CTX_ + E_) + CTX_ + k);
    bf16x4 o; o[0]=f2bf(v.x); o[1]=f2bf(v.y); o[2]=f2bf(v.z); o[3]=f2bf(v.w);
    *(bf16x4*)(dst + (size_t)e) = o;
}

// X[t*64+b][k] = bf16(emb[seq[t*64+b]][k])  -> [4096][512]
__global__ __launch_bounds__(256) void k_gather_x(const int* __restrict__ seq,
                                                  const float* __restrict__ emb,
                                                  __bf16* __restrict__ dst) {
    int i = blockIdx.x * 256 + threadIdx.x;
    int e = i * 4, r = e >> 9, k = e & 511;
    int tok = seq[r];
    float4 v = *(const float4*)(emb + (size_t)tok * E_ + k);
    bf16x4 o; o[0]=f2bf(v.x); o[1]=f2bf(v.y); o[2]=f2bf(v.z); o[3]=f2bf(v.w);
    *(bf16x4*)(dst + (size_t)e) = o;
}

// ---------------- init state: h0 (bf16) , c0 (f32) ----------------
__global__ __launch_bounds__(256) void k_init(const float* __restrict__ ctx,
                                              const float* __restrict__ WS, const float* __restrict__ bS,
                                              const float* __restrict__ WC, const float* __restrict__ bC,
                                              __bf16* __restrict__ h0, float* __restrict__ c0) {
    int idx = blockIdx.x * 256 + threadIdx.x;   // 32768
    int r = idx >> 4, bg = idx & 15;
    int sel = r >> 10, u = r & 1023;
    const float4* w = (const float4*)((sel ? WC : WS) + (size_t)u * CTX_);
    float acc[4] = {0.f,0.f,0.f,0.f};
    for (int k = 0; k < 256; ++k) {
        float4 wv = w[k];
#pragma unroll
        for (int i = 0; i < 4; ++i) {
            float4 cv = *(const float4*)(ctx + (size_t)(bg + 16*i) * CTX_ + k * 4);
            acc[i] += wv.x*cv.x + wv.y*cv.y + wv.z*cv.z + wv.w*cv.w;
        }
    }
    float bias = sel ? bC[u] : bS[u];
#pragma unroll
    for (int i = 0; i < 4; ++i) {
        int b = bg + 16*i;
        float v = tanhf(acc[i] + bias);
        if (sel) c0[(size_t)b * H_ + u] = v;
        else     h0[(size_t)b * H_ + u] = f2bf(v);
    }
}

// ---------------- ctx_gates[b][j] = ctx[b]·W_ih[j][0:CTX] + b_ih[j] + b_hh[j] ----------------
__global__ __launch_bounds__(256) void k_ctxgates(const float* __restrict__ ctx,
                                                  const float* __restrict__ Wih,
                                                  const float* __restrict__ bih,
                                                  const float* __restrict__ bhh,
                                                  float* __restrict__ out) {
    int idx = blockIdx.x * 256 + threadIdx.x;   // 65536
    int j = idx >> 4, bg = idx & 15;
    const float4* w = (const float4*)(Wih + (size_t)j * (CTX_ + E_));
    float acc[4] = {0.f,0.f,0.f,0.f};
    for (int k = 0; k < 256; ++k) {
        float4 wv = w[k];
#pragma unroll
        for (int i = 0; i < 4; ++i) {
            float4 cv = *(const float4*)(ctx + (size_t)(bg + 16*i) * CTX_ + k * 4);
            acc[i] += wv.x*cv.x + wv.y*cv.y + wv.z*cv.z + wv.w*cv.w;
        }
    }
    float bias = bih[j] + bhh[j];
#pragma unroll
    for (int i = 0; i < 4; ++i) out[(size_t)(bg + 16*i) * FH_ + j] = acc[i] + bias;
}

// ---------------- fused per-step kernel ----------------
// blocks [0, n_gates): gates GEMM (M=64, K=1024(h)+512(emb)) + cell update
//   block n owns j in {g*1024 + n*32 + ul : g=0..3, ul=0..31}
// blocks [n_gates, n_gates+8): d1 GEMM for PREVIOUS step (M=64, K=2048, N=1024)
__global__ __launch_bounds__(256) void k_step(
    const __bf16* __restrict__ h_in, __bf16* __restrict__ h_out,
    const __bf16* __restrict__ Whh, const __bf16* __restrict__ WihE,
    const __bf16* __restrict__ Xb, const float* __restrict__ ctxg,
    float* __restrict__ c, __bf16* __restrict__ hc_out,
    const __bf16* __restrict__ hc_in, const __bf16* __restrict__ Wd1,
    const float* __restrict__ b_d1, __bf16* __restrict__ hid_out,
    int t, int n_gates) {
    __shared__ __align__(16) char smem[45056];
    __bf16* Als = (__bf16*)smem;            // [64][32]
    __bf16* Bls = (__bf16*)(smem + 4096);   // [128][32]
    float*  gsm = (float*)(smem + 12288);   // [64][128]

    const int tid = threadIdx.x, lane = tid & 63, wave = tid >> 6;
    const int srow = wave * 16 + (lane >> 2);   // staging row 0..63
    const int scol = (lane & 3) * 8;            // staging col 0,8,16,24
    const int fr = lane & 15, fq = lane >> 4;   // fragment row / k-quad
    const int wn = wave;                        // wave n-window (32 wide)

    f32x4 acc[4][2];
#pragma unroll
    for (int i = 0; i < 4; ++i)
#pragma unroll
        for (int j = 0; j < 2; ++j) acc[i][j] = (f32x4){0.f,0.f,0.f,0.f};

    if ((int)blockIdx.x < n_gates) {
        const int u0 = blockIdx.x * 32;
        const int nlA = srow, nlB = srow + 64;
        const int jA = (nlA >> 5) * H_ + u0 + (nlA & 31);
        const int jB = (nlB >> 5) * H_ + u0 + (nlB & 31);
        for (int kt = 0; kt < 48; ++kt) {
            const int k0 = kt * 32;
            const void *ag, *bg0, *bg1;
            if (k0 < 1024) {
                ag  = h_in + (size_t)srow * H_ + k0 + scol;
                bg0 = Whh + (size_t)jA * H_ + k0 + scol;
                bg1 = Whh + (size_t)jB * H_ + k0 + scol;
            } else {
                const int kx = k0 - 1024;
                ag  = Xb + (size_t)(t * 64 + srow) * E_ + kx + scol;
                bg0 = WihE + (size_t)jA * E_ + kx + scol;
                bg1 = WihE + (size_t)jB * E_ + kx + scol;
            }
            GL(ag,  smem + wave * 1024);
            GL(bg0, smem + 4096 + wave * 1024);
            GL(bg1, smem + 8192 + wave * 1024);
            __syncthreads();
            bf16x8 af[4], bfr[2];
#pragma unroll
            for (int mi = 0; mi < 4; ++mi)
                af[mi] = *(const bf16x8*)(Als + (mi*16 + fr) * 32 + fq * 8);
#pragma unroll
            for (int ni = 0; ni < 2; ++ni)
                bfr[ni] = *(const bf16x8*)(Bls + (wn*32 + ni*16 + fr) * 32 + fq * 8);
#pragma unroll
            for (int mi = 0; mi < 4; ++mi)
#pragma unroll
                for (int ni = 0; ni < 2; ++ni)
                    acc[mi][ni] = __builtin_amdgcn_mfma_f32_16x16x32_bf16(af[mi], bfr[ni], acc[mi][ni], 0, 0, 0);
            __syncthreads();
        }
        // epilogue: acc + ctx_gates  -> LDS
        const int cr = fq * 4, cc = fr;
#pragma unroll
        for (int mi = 0; mi < 4; ++mi)
#pragma unroll
            for (int ni = 0; ni < 2; ++ni) {
                const int nl = wn*32 + ni*16 + cc;
                const int j  = (nl >> 5) * H_ + u0 + (nl & 31);
#pragma unroll
                for (int r = 0; r < 4; ++r) {
                    const int b = mi*16 + cr + r;
                    gsm[b * 128 + nl] = acc[mi][ni][r] + ctxg[(size_t)b * FH_ + j];
                }
            }
        __syncthreads();
        // fused cell update (this block owns u in [u0, u0+32) for all b)
#pragma unroll
        for (int i = 0; i < 8; ++i) {
            const int idx = tid + 256 * i;   // 0..2047
            const int b = idx >> 5, ul = idx & 31, u = u0 + ul;
            const float gi = gsm[b*128 + ul];
            const float gf = gsm[b*128 + 32 + ul];
            const float gg = gsm[b*128 + 64 + ul];
            const float go = gsm[b*128 + 96 + ul];
            const float cv = c[(size_t)b * H_ + u];
            const float cn = sigm(gf) * cv + sigm(gi) * tanhf(gg);
            const float hn = sigm(go) * tanhf(cn);
            c[(size_t)b * H_ + u] = cn;
            h_out[(size_t)b * H_ + u] = f2bf(hn);
            hc_out[(size_t)b * 2048 + u] = f2bf(hn);
            hc_out[(size_t)b * 2048 + H_ + u] = f2bf(cn);
        }
    } else {
        // d1 path: hid = tanh([h|c] @ W_d1^T + b_d1), previous step's hc
        const int v0 = ((int)blockIdx.x - n_gates) * 128;
        for (int kt = 0; kt < 64; ++kt) {
            const int k0 = kt * 32;
            GL(hc_in + (size_t)srow * 2048 + k0 + scol,        smem + wave * 1024);
            GL(Wd1 + (size_t)(v0 + srow) * 2048 + k0 + scol,   smem + 4096 + wave * 1024);
            GL(Wd1 + (size_t)(v0 + 64 + srow) * 2048 + k0 + scol, smem + 8192 + wave * 1024);
            __syncthreads();
            bf16x8 af[4], bfr[2];
#pragma unroll
            for (int mi = 0; mi < 4; ++mi)
                af[mi] = *(const bf16x8*)(Als + (mi*16 + fr) * 32 + fq * 8);
#pragma unroll
            for (int ni = 0; ni < 2; ++ni)
                bfr[ni] = *(const bf16x8*)(Bls + (wn*32 + ni*16 + fr) * 32 + fq * 8);
#pragma unroll
            for (int mi = 0; mi < 4; ++mi)
#pragma unroll
                for (int ni = 0; ni < 2; ++ni)
                    acc[mi][ni] = __builtin_amdgcn_mfma_f32_16x16x32_bf16(af[mi], bfr[ni], acc[mi][ni], 0, 0, 0);
            __syncthreads();
        }
        const int cr = fq * 4, cc = fr;
#pragma unroll
        for (int mi = 0; mi < 4; ++mi)
#pragma unroll
            for (int ni = 0; ni < 2; ++ni) {
                const int v = v0 + wn*32 + ni*16 + cc;
                const float bv = b_d1[v];
#pragma unroll
                for (int r = 0; r < 4; ++r) {
                    const int b = mi*16 + cr + r;
                    hid_out[(size_t)b * H_ + v] = f2bf(tanhf(acc[mi][ni][r] + bv));
                }
            }
    }
}

// ---------------- big GEMM: C[M,N] = A[M,K] * Bt[N,K]^T + bias (m97-style 128x128 tile) ----------------
__global__ __launch_bounds__(256) void k_gemm_bt(const __bf16* __restrict__ A,
                                                 const __bf16* __restrict__ Bt,
                                                 const float* __restrict__ bias,
                                                 float* __restrict__ C,
                                                 int M, int N, int K) {
    __shared__ __align__(16) char smem[16384];
    __bf16* Als = (__bf16*)smem;            // [128][32]
    __bf16* Bls = (__bf16*)(smem + 8192);   // [128][32]
    const int tid = threadIdx.x, lane = tid & 63, wave = tid >> 6;
    const int wm = wave >> 1, wn = wave & 1;
    const int bm = blockIdx.y * 128, bn = blockIdx.x * 128;
    const int srow = wave * 16 + (lane >> 2);
    const int scol = (lane & 3) * 8;
    const int fr = lane & 15, fq = lane >> 4;

    f32x4 acc[4][4];
#pragma unroll
    for (int i = 0; i < 4; ++i)
#pragma unroll
        for (int j = 0; j < 4; ++j) acc[i][j] = (f32x4){0.f,0.f,0.f,0.f};

    const int nkt = K >> 5;
    for (int kt = 0; kt < nkt; ++kt) {
        const int k0 = kt << 5;
        GL(A  + (size_t)(bm + srow) * K + k0 + scol,      smem + wave * 1024);
        GL(A  + (size_t)(bm + 64 + srow) * K + k0 + scol, smem + 4096 + wave * 1024);
        GL(Bt + (size_t)(bn + srow) * K + k0 + scol,      smem + 8192 + wave * 1024);
        GL(Bt + (size_t)(bn + 64 + srow) * K + k0 + scol, smem + 12288 + wave * 1024);
        __syncthreads();
        bf16x8 af[4], bfr[4];
#pragma unroll
        for (int mi = 0; mi < 4; ++mi)
            af[mi] = *(const bf16x8*)(Als + (wm*64 + mi*16 + fr) * 32 + fq * 8);
#pragma unroll
        for (int ni = 0; ni < 4; ++ni)
            bfr[ni] = *(const bf16x8*)(Bls + (wn*64 + ni*16 + fr) * 32 + fq * 8);
#pragma unroll
        for (int mi = 0; mi < 4; ++mi)
#pragma unroll
            for (int ni = 0; ni < 4; ++ni)
                acc[mi][ni] = __builtin_amdgcn_mfma_f32_16x16x32_bf16(af[mi], bfr[ni], acc[mi][ni], 0, 0, 0);
        __syncthreads();
    }
    const int cr = fq * 4, cc = fr;
#pragma unroll
    for (int ni = 0; ni < 4; ++ni) {
        const int gc = bn + wn*64 + ni*16 + cc;
        const float bv = bias ? bias[gc] : 0.f;
#pragma unroll
        for (int mi = 0; mi < 4; ++mi) {
            const int gr = bm + wm*64 + mi*16 + cr;
            float* cp = C + (size_t)gr * N + gc;
#pragma unroll
            for (int r = 0; r < 4; ++r) cp[(size_t)r * N] = acc[mi][ni][r] + bv;
        }
    }
}

extern "C" void kernel_launch(void* const* d_in, const int* in_sizes, int n_in,
                              void* d_out, int out_size, void* d_ws, size_t ws_size,
                              hipStream_t stream) {
    const int*   seq     = (const int*)d_in[0];
    const float* ctx     = (const float*)d_in[1];
    const float* emb     = (const float*)d_in[2];
    const float* W_ih    = (const float*)d_in[3];
    const float* b_ih    = (const float*)d_in[4];
    const float* W_hh    = (const float*)d_in[5];
    const float* b_hh    = (const float*)d_in[6];
    const float* W_initS = (const float*)d_in[7];
    const float* b_initS = (const float*)d_in[8];
    const float* W_initC = (const float*)d_in[9];
    const float* b_initC = (const float*)d_in[10];
    const float* W_d1    = (const float*)d_in[11];
    const float* b_d1    = (const float*)d_in[12];
    const float* W_d2    = (const float*)d_in[13];
    const float* b_d2    = (const float*)d_in[14];
    float* out = (float*)d_out;

    // workspace layout (needs ~97 MB)
    char* ws = (char*)d_ws;
    __bf16* Whh_bf  = (__bf16*)(ws + 0);                    //  8 MiB
    __bf16* WihE_bf = (__bf16*)(ws + (8u << 20));           //  4 MiB
    __bf16* Wd1_bf  = (__bf16*)(ws + (12u << 20));          //  4 MiB
    __bf16* Wd2_bf  = (__bf16*)(ws + (16u << 20));          //  62.5 MiB
    __bf16* X_bf    = (__bf16*)(ws + 82313216u);            //  4 MiB
    float*  ctxg    = (float*) (ws + 86507520u);            //  1 MiB
    __bf16* hbuf0   = (__bf16*)(ws + 87556096u);            //  128 KiB
    __bf16* hbuf1   = (__bf16*)(ws + 87687168u);            //  128 KiB
    float*  cbuf    = (float*) (ws + 87818240u);            //  256 KiB
    __bf16* hc0     = (__bf16*)(ws + 88080384u);            //  256 KiB
    __bf16* hc1     = (__bf16*)(ws + 88342528u);            //  256 KiB
    __bf16* hid     = (__bf16*)(ws + 88604672u);            //  8 MiB

    // one-time precompute
    k_cast<<<4096, 256, 0, stream>>>(W_hh, Whh_bf, 1048576);
    k_cast_wihe<<<2048, 256, 0, stream>>>(W_ih, WihE_bf);
    k_cast<<<2048, 256, 0, stream>>>(W_d1, Wd1_bf, 524288);
    k_cast<<<32000, 256, 0, stream>>>(W_d2, Wd2_bf, 8192000);
    k_gather_x<<<2048, 256, 0, stream>>>(seq, emb, X_bf);
    k_init<<<128, 256, 0, stream>>>(ctx, W_initS, b_initS, W_initC, b_initC, hbuf0, cbuf);
    k_ctxgates<<<256, 256, 0, stream>>>(ctx, W_ih, b_ih, b_hh, ctxg);

    // recurrence: F(t) = gates+cell(t) [blocks 0..31] + d1(t-1) [blocks 32..39]
    for (int t = 0; t < T_; ++t) {
        __bf16* h_in  = (t & 1) ? hbuf1 : hbuf0;
        __bf16* h_out = (t & 1) ? hbuf0 : hbuf1;
        __bf16* hco   = (t & 1) ? hc1 : hc0;
        __bf16* hci   = (t & 1) ? hc0 : hc1;   // = hc[(t-1)&1]
        __bf16* hid_o = (t == 0) ? hid : hid + (size_t)(t - 1) * (B_ * H_);
        int grid = (t == 0) ? 32 : 40;
        k_step<<<grid, 256, 0, stream>>>(h_in, h_out, Whh_bf, WihE_bf, X_bf, ctxg,
                                         cbuf, hco, hci, Wd1_bf, b_d1, hid_o, t, 32);
    }
    // final d1 (step 63): reads hc[63&1] = hc1
    k_step<<<8, 256, 0, stream>>>(hbuf0, hbuf1, Whh_bf, WihE_bf, X_bf, ctxg,
                                  cbuf, hc0, hc1, Wd1_bf, b_d1,
                                  hid + (size_t)63 * (B_ * H_), 64, 0);

    // out[T*B, V] = hid @ W_d2^T + b_d2
    k_gemm_bt<<<dim3(V_ / 128, (T_ * B_) / 128), 256, 0, stream>>>(
        hid, Wd2_bf, b_d2, out, T_ * B_, V_, H_);
}